// Round 1
// baseline (1370.309 us; speedup 1.0000x reference)
//
#include <hip/hip_runtime.h>
#include <hip/hip_bf16.h>

#define NIMG 8
#define HW 56
#define CDIM 256
#define TOK (NIMG*HW*HW)        // 25088
#define NWIN 49
#define NPW (NIMG*NWIN)         // 392
#define ATT_SCALE 0.0625f       // 256^-0.5

// workspace offsets (bytes), all 16B aligned
static const size_t OFF_XLN   = 0;            // T*256 f32 (reused as ywo)
static const size_t OFF_QKV   = 25690112;     // T*768 f32 (reused as hmid bf16)
static const size_t OFF_QKWIN = 102760448;    // 392*512 f32
static const size_t OFF_RIDX  = 103563264;    // 392*4 int
static const size_t OFF_ATTN  = 103569536;    // T*256 f32 (reused as h2)

__device__ __forceinline__ float gelu_exact(float v) {
    return 0.5f * v * (1.f + erff(v * 0.70710678118654752f));
}

// ---------------- LayerNorm (one token per block, 256 ch) ----------------
__global__ __launch_bounds__(256) void ln_k(const float* __restrict__ in,
                                            const float* __restrict__ g,
                                            const float* __restrict__ b,
                                            float* __restrict__ out, int remap) {
    int t = blockIdx.x;
    int c = threadIdx.x;
    float v = in[(size_t)t * 256 + c];
    float s = v, s2 = v * v;
    #pragma unroll
    for (int o = 32; o > 0; o >>= 1) {
        s  += __shfl_down(s, o);
        s2 += __shfl_down(s2, o);
    }
    __shared__ float ps[4], ps2[4], stats[2];
    int wid = c >> 6, lane = c & 63;
    if (lane == 0) { ps[wid] = s; ps2[wid] = s2; }
    __syncthreads();
    if (c == 0) {
        float ts = ps[0] + ps[1] + ps[2] + ps[3];
        float ts2 = ps2[0] + ps2[1] + ps2[2] + ps2[3];
        float mu = ts * (1.f / 256.f);
        float var = ts2 * (1.f / 256.f) - mu * mu;
        stats[0] = mu;
        stats[1] = rsqrtf(var + 1e-6f);
    }
    __syncthreads();
    float r = (v - stats[0]) * stats[1] * g[c] + b[c];
    size_t ot;
    if (remap) {
        int n = t / 3136, rem = t % 3136, y = rem / 56, x = rem % 56;
        int p = (y >> 3) * 7 + (x >> 3);
        int si = (y & 7) * 8 + (x & 7);
        ot = ((size_t)(n * 49 + p) * 64 + si) * 256 + c;
    } else {
        ot = (size_t)t * 256 + c;
    }
    out[ot] = r;
}

// ---------------- generic fp32 tiled GEMM: C[M,N] = A[M,K]@B[K,N] ----------------
// MODE 0: +bias. MODE 1: +bias+res. MODE 2: gelu(+bias) -> bf16 out.
template<int MODE, bool ABF16>
__global__ __launch_bounds__(256) void gemm_k(const void* Av, const float* __restrict__ B,
                                              const float* __restrict__ bias,
                                              const float* res, void* Cv,
                                              int M, int N, int K) {
    const int bn = blockIdx.x * 128;
    const int bm = blockIdx.y * 128;
    const int tid = threadIdx.x;
    const int tx = tid & 15, ty = tid >> 4;
    __shared__ float As[16][132];
    __shared__ float Bs[16][132];
    float acc[8][8] = {};
    for (int k0 = 0; k0 < K; k0 += 16) {
        // A tile: 128 rows x 16 k, transposed into As[k][row]
        if (!ABF16) {
            const float* A = (const float*)Av;
            #pragma unroll
            for (int u = 0; u < 2; ++u) {
                int idx = tid * 2 + u;          // 0..511
                int row = idx >> 2;
                int kq = (idx & 3) * 4;
                float4 v = *(const float4*)(A + (size_t)(bm + row) * K + k0 + kq);
                As[kq + 0][row] = v.x;
                As[kq + 1][row] = v.y;
                As[kq + 2][row] = v.z;
                As[kq + 3][row] = v.w;
            }
        } else {
            const __hip_bfloat16* A = (const __hip_bfloat16*)Av;
            #pragma unroll
            for (int u = 0; u < 2; ++u) {
                int idx = tid * 2 + u;
                int row = idx >> 2;
                int kq = (idx & 3) * 4;
                uint2 uv = *(const uint2*)(A + (size_t)(bm + row) * K + k0 + kq);
                As[kq + 0][row] = __uint_as_float(uv.x << 16);
                As[kq + 1][row] = __uint_as_float(uv.x & 0xffff0000u);
                As[kq + 2][row] = __uint_as_float(uv.y << 16);
                As[kq + 3][row] = __uint_as_float(uv.y & 0xffff0000u);
            }
        }
        // B tile: 16 k x 128 n
        #pragma unroll
        for (int u = 0; u < 2; ++u) {
            int idx = tid * 2 + u;
            int kk = idx >> 5;
            int nq = (idx & 31) * 4;
            float4 v = *(const float4*)(B + (size_t)(k0 + kk) * N + bn + nq);
            *(float4*)&Bs[kk][nq] = v;
        }
        __syncthreads();
        #pragma unroll
        for (int kk = 0; kk < 16; ++kk) {
            float ra[8], rb[8];
            *(float4*)&ra[0] = *(const float4*)&As[kk][ty * 8];
            *(float4*)&ra[4] = *(const float4*)&As[kk][ty * 8 + 4];
            *(float4*)&rb[0] = *(const float4*)&Bs[kk][tx * 8];
            *(float4*)&rb[4] = *(const float4*)&Bs[kk][tx * 8 + 4];
            #pragma unroll
            for (int i = 0; i < 8; ++i)
                #pragma unroll
                for (int j = 0; j < 8; ++j)
                    acc[i][j] += ra[i] * rb[j];
        }
        __syncthreads();
    }
    #pragma unroll
    for (int i = 0; i < 8; ++i) {
        int row = bm + ty * 8 + i;
        #pragma unroll
        for (int j = 0; j < 8; ++j) {
            int col = bn + tx * 8 + j;
            float v = acc[i][j] + bias[col];
            if (MODE == 1) v += res[(size_t)row * N + col];
            if (MODE == 2) {
                ((__hip_bfloat16*)Cv)[(size_t)row * N + col] = __float2bfloat16(gelu_exact(v));
            } else {
                ((float*)Cv)[(size_t)row * N + col] = v;
            }
        }
    }
}

// ---------------- window means of q,k: qkwin[w][0:256]=q_win, [256:512]=k_win ----------------
__global__ __launch_bounds__(512) void win_means_k(const float* __restrict__ qkv,
                                                   float* __restrict__ qkwin) {
    int w = blockIdx.x;
    int c = threadIdx.x;   // 0..511 covers q (0..255) and k (256..511)
    const float* base = qkv + (size_t)w * 64 * 768 + c;
    float s = 0.f;
    #pragma unroll 8
    for (int si = 0; si < 64; ++si) s += base[(size_t)si * 768];
    qkwin[(size_t)w * 512 + c] = s * (1.f / 64.f);
}

// ---------------- routing top-k (one block per window) ----------------
__global__ __launch_bounds__(64) void route_k(const float* __restrict__ qkwin,
                                              int* __restrict__ ridx) {
    int w = blockIdx.x;
    int n = w / 49;
    int tid = threadIdx.x;
    __shared__ float qv[256];
    __shared__ float lg[49];
    for (int i = tid; i < 256; i += 64) qv[i] = qkwin[(size_t)w * 512 + i] * ATT_SCALE;
    __syncthreads();
    if (tid < 49) {
        const float* kp = qkwin + (size_t)(n * 49 + tid) * 512 + 256;
        float d = 0.f;
        for (int cc = 0; cc < 256; ++cc) d += qv[cc] * kp[cc];
        lg[tid] = d;
    }
    __syncthreads();
    if (tid == 0) {
        #pragma unroll
        for (int t = 0; t < 4; ++t) {
            float best = -1e30f; int bi = 0;
            for (int j = 0; j < 49; ++j)
                if (lg[j] > best) { best = lg[j]; bi = j; }
            lg[bi] = -1e30f;
            ridx[w * 4 + t] = bi;
        }
    }
}

// ---------------- attention: block per window, wave per head, lane per query row ----------------
__global__ __launch_bounds__(512) void attn_k(const float* __restrict__ qkv,
                                              const int* __restrict__ ridx,
                                              float* __restrict__ attn) {
    int w = blockIdx.x;
    int n = w / 49;
    int tid = threadIdx.x;
    int mh = tid >> 6;     // head
    int r = tid & 63;      // query row
    __shared__ int rs[4];
    if (tid < 4) rs[tid] = ridx[w * 4 + tid];
    __syncthreads();
    float q[32];
    const float* qp = qkv + ((size_t)w * 64 + r) * 768 + mh * 32;
    #pragma unroll
    for (int i = 0; i < 8; ++i) {
        float4 v4 = *(const float4*)(qp + i * 4);
        q[i * 4 + 0] = v4.x; q[i * 4 + 1] = v4.y; q[i * 4 + 2] = v4.z; q[i * 4 + 3] = v4.w;
    }
    float m = -1e30f, l = 0.f;
    float acc[32];
    #pragma unroll
    for (int i = 0; i < 32; ++i) acc[i] = 0.f;
    for (int t = 0; t < 4; ++t) {
        const float* kbase = qkv + (size_t)(n * 49 + rs[t]) * 64 * 768 + 256 + mh * 32;
        for (int s = 0; s < 64; ++s) {
            const float* kp = kbase + (size_t)s * 768;
            float d = 0.f;
            #pragma unroll
            for (int i = 0; i < 8; ++i) {
                float4 kv4 = *(const float4*)(kp + i * 4);
                d += q[i * 4 + 0] * kv4.x + q[i * 4 + 1] * kv4.y
                   + q[i * 4 + 2] * kv4.z + q[i * 4 + 3] * kv4.w;
            }
            float sc = d * ATT_SCALE;
            float nm = fmaxf(m, sc);
            float corr = __expf(m - nm);
            float pe = __expf(sc - nm);
            l = l * corr + pe;
            const float* vp = kp + 256;
            #pragma unroll
            for (int i = 0; i < 8; ++i) {
                float4 vv = *(const float4*)(vp + i * 4);
                acc[i * 4 + 0] = acc[i * 4 + 0] * corr + pe * vv.x;
                acc[i * 4 + 1] = acc[i * 4 + 1] * corr + pe * vv.y;
                acc[i * 4 + 2] = acc[i * 4 + 2] * corr + pe * vv.z;
                acc[i * 4 + 3] = acc[i * 4 + 3] * corr + pe * vv.w;
            }
            m = nm;
        }
    }
    float inv = 1.f / l;
    float* op = attn + ((size_t)w * 64 + r) * 256 + mh * 32;
    #pragma unroll
    for (int i = 0; i < 8; ++i) {
        float4 o4;
        o4.x = acc[i * 4 + 0] * inv;
        o4.y = acc[i * 4 + 1] * inv;
        o4.z = acc[i * 4 + 2] * inv;
        o4.w = acc[i * 4 + 3] * inv;
        *(float4*)(op + i * 4) = o4;
    }
}

// ---------------- LePE 5x5 depthwise conv + combine with attention out ----------------
__global__ __launch_bounds__(256) void lepe_k(const float* __restrict__ qkv,
                                              const float* __restrict__ attn,
                                              const float* __restrict__ lw,
                                              const float* __restrict__ lb,
                                              float* __restrict__ ywo) {
    int t = blockIdx.x;
    int c = threadIdx.x;
    int n = t / 3136, rem = t % 3136, y = rem / 56, x = rem % 56;
    float sum = lb[c];
    #pragma unroll
    for (int ky = 0; ky < 5; ++ky) {
        int yy = y + ky - 2;
        if ((unsigned)yy >= 56u) continue;
        #pragma unroll
        for (int kx = 0; kx < 5; ++kx) {
            int xx = x + kx - 2;
            if ((unsigned)xx >= 56u) continue;
            int p = (yy >> 3) * 7 + (xx >> 3);
            int si = (yy & 7) * 8 + (xx & 7);
            sum += qkv[((size_t)(n * 49 + p) * 64 + si) * 768 + 512 + c]
                 * lw[(ky * 5 + kx) * 256 + c];
        }
    }
    int p0 = (y >> 3) * 7 + (x >> 3);
    int s0 = (y & 7) * 8 + (x & 7);
    sum += attn[((size_t)(n * 49 + p0) * 64 + s0) * 256 + c];
    ywo[(size_t)t * 256 + c] = sum;
}

extern "C" void kernel_launch(void* const* d_in, const int* in_sizes, int n_in,
                              void* d_out, int out_size, void* d_ws, size_t ws_size,
                              hipStream_t stream) {
    const float* x      = (const float*)d_in[0];
    const float* ln1_g  = (const float*)d_in[1];
    const float* ln1_b  = (const float*)d_in[2];
    const float* qkv_w  = (const float*)d_in[3];
    const float* qkv_b  = (const float*)d_in[4];
    const float* lepe_w = (const float*)d_in[5];
    const float* lepe_b = (const float*)d_in[6];
    const float* wo_w   = (const float*)d_in[7];
    const float* wo_b   = (const float*)d_in[8];
    const float* ln2_g  = (const float*)d_in[9];
    const float* ln2_b  = (const float*)d_in[10];
    const float* mlp_w1 = (const float*)d_in[11];
    const float* mlp_b1 = (const float*)d_in[12];
    const float* mlp_w2 = (const float*)d_in[13];
    const float* mlp_b2 = (const float*)d_in[14];
    float* out = (float*)d_out;

    char* ws = (char*)d_ws;
    float* xln    = (float*)(ws + OFF_XLN);
    float* qkv    = (float*)(ws + OFF_QKV);
    float* qkwin  = (float*)(ws + OFF_QKWIN);
    int*   ridx   = (int*)(ws + OFF_RIDX);
    float* attn   = (float*)(ws + OFF_ATTN);
    float* ywo    = (float*)(ws + OFF_XLN);            // reuse xln
    float* h2     = (float*)(ws + OFF_ATTN);           // reuse attn
    __hip_bfloat16* hmid = (__hip_bfloat16*)(ws + OFF_QKV);  // reuse qkv

    // 1. LN1 -> xln (window order)
    ln_k<<<TOK, 256, 0, stream>>>(x, ln1_g, ln1_b, xln, 1);
    // 2. qkv GEMM: (T,256)@(256,768)
    gemm_k<0, false><<<dim3(768 / 128, TOK / 128), 256, 0, stream>>>(
        xln, qkv_w, qkv_b, nullptr, qkv, TOK, 768, 256);
    // 3. window means
    win_means_k<<<NPW, 512, 0, stream>>>(qkv, qkwin);
    // 4. routing top-k
    route_k<<<NPW, 64, 0, stream>>>(qkwin, ridx);
    // 5. attention
    attn_k<<<NPW, 512, 0, stream>>>(qkv, ridx, attn);
    // 6. lepe + combine -> ywo (image order)
    lepe_k<<<TOK, 256, 0, stream>>>(qkv, attn, lepe_w, lepe_b, ywo);
    // 7. wo GEMM + x residual -> d_out
    gemm_k<1, false><<<dim3(256 / 128, TOK / 128), 256, 0, stream>>>(
        ywo, wo_w, wo_b, x, out, TOK, 256, 256);
    // 8. LN2 -> h2
    ln_k<<<TOK, 256, 0, stream>>>(out, ln2_g, ln2_b, h2, 0);
    // 9. MLP1 GEMM + gelu -> hmid (bf16)
    gemm_k<2, false><<<dim3(1024 / 128, TOK / 128), 256, 0, stream>>>(
        h2, mlp_w1, mlp_b1, nullptr, hmid, TOK, 1024, 256);
    // 10. MLP2 GEMM (bf16 A) + bias + d_out residual -> d_out
    gemm_k<1, true><<<dim3(256 / 128, TOK / 128), 256, 0, stream>>>(
        hmid, mlp_w2, mlp_b2, out, out, TOK, 256, 1024);
}

// Round 2
// 436.588 us; speedup vs baseline: 3.1387x; 3.1387x over previous
//
#include <hip/hip_runtime.h>
#include <hip/hip_bf16.h>

#define NIMG 8
#define HW 56
#define CDIM 256
#define TOK (NIMG*HW*HW)        // 25088
#define NWIN 49
#define NPW (NIMG*NWIN)         // 392
#define ATT_SCALE 0.0625f       // 256^-0.5

typedef __attribute__((ext_vector_type(8))) short short8;
typedef __attribute__((ext_vector_type(4))) float f32x4;

// ---- workspace layout (bytes, 16B aligned) ----
static const size_t OFF_WQKV  = 0;           // 768x256 bf16
static const size_t OFF_WWO   = 393216;      // 256x256 bf16
static const size_t OFF_W1    = 524288;      // 1024x256 bf16
static const size_t OFF_W2    = 1048576;     // 256x1024 bf16
static const size_t OFF_XLN   = 1572864;     // 25088x256 bf16 (reused: ywo_bf; with QKV as hmid)
static const size_t OFF_QKV   = 14417920;    // 25088x768 bf16
static const size_t OFF_QKWIN = 52953088;    // 392x512 f32
static const size_t OFF_RIDX  = 53755904;    // 392x4 int
static const size_t OFF_ATTN  = 53762176;    // 25088x256 f32 (reused: h2_bf)
static const size_t OFF_HMID  = OFF_XLN;     // 25088x1024 bf16 spans XLN+QKV regions

__device__ __forceinline__ float gelu_exact(float v) {
    return 0.5f * v * (1.f + erff(v * 0.70710678118654752f));
}
__device__ __forceinline__ short f2bs(float x) {
    __hip_bfloat16 h = __float2bfloat16(x);
    return *(short*)&h;
}

// ---------------- weight transpose + cast: src K x N f32 -> dst N x K bf16 ----------------
__global__ __launch_bounds__(256) void transpose_cast_k(const float* __restrict__ src,
                                                        __hip_bfloat16* __restrict__ dst,
                                                        int K, int N) {
    __shared__ float t[32][33];
    int n0 = blockIdx.x * 32, k0 = blockIdx.y * 32;
    int tx = threadIdx.x & 31, ty = threadIdx.x >> 5;   // 32 x 8
    #pragma unroll
    for (int i = 0; i < 32; i += 8)
        t[ty + i][tx] = src[(size_t)(k0 + ty + i) * N + n0 + tx];
    __syncthreads();
    #pragma unroll
    for (int i = 0; i < 32; i += 8)
        dst[(size_t)(n0 + ty + i) * K + k0 + tx] = __float2bfloat16(t[tx][ty + i]);
}

// ---------------- LayerNorm (one token per block, 256 ch) -> bf16 out ----------------
__global__ __launch_bounds__(256) void ln_bf_k(const float* __restrict__ in,
                                               const float* __restrict__ g,
                                               const float* __restrict__ b,
                                               __hip_bfloat16* __restrict__ out, int remap) {
    int t = blockIdx.x;
    int c = threadIdx.x;
    float v = in[(size_t)t * 256 + c];
    float s = v, s2 = v * v;
    #pragma unroll
    for (int o = 32; o > 0; o >>= 1) {
        s  += __shfl_down(s, o);
        s2 += __shfl_down(s2, o);
    }
    __shared__ float ps[4], ps2[4], stats[2];
    int wid = c >> 6, lane = c & 63;
    if (lane == 0) { ps[wid] = s; ps2[wid] = s2; }
    __syncthreads();
    if (c == 0) {
        float ts = ps[0] + ps[1] + ps[2] + ps[3];
        float ts2 = ps2[0] + ps2[1] + ps2[2] + ps2[3];
        float mu = ts * (1.f / 256.f);
        float var = ts2 * (1.f / 256.f) - mu * mu;
        stats[0] = mu;
        stats[1] = rsqrtf(var + 1e-6f);
    }
    __syncthreads();
    float r = (v - stats[0]) * stats[1] * g[c] + b[c];
    size_t ot;
    if (remap) {
        int n = t / 3136, rem = t % 3136, y = rem / 56, x = rem % 56;
        int p = (y >> 3) * 7 + (x >> 3);
        int si = (y & 7) * 8 + (x & 7);
        ot = ((size_t)(n * 49 + p) * 64 + si) * 256 + c;
    } else {
        ot = (size_t)t * 256 + c;
    }
    out[ot] = __float2bfloat16(r);
}

// ---------------- bf16 MFMA GEMM: C[M,N] = A[M,K] @ Bt[N,K]^T ----------------
// MODE 0: bf16 out, +bias. MODE 1: f32 out, +bias+res. MODE 2: bf16 out, gelu(+bias).
template<int MODE>
__global__ __launch_bounds__(256) void gemm_bf(const short* __restrict__ A,
                                               const short* __restrict__ Bt,
                                               const float* __restrict__ bias,
                                               const float* __restrict__ res, void* Cv,
                                               int M, int N, int K) {
    const int bn = blockIdx.x * 128;
    const int bm = blockIdx.y * 128;
    const int tid = threadIdx.x;
    const int wave = tid >> 6, lane = tid & 63;
    const int l15 = lane & 15, quad = lane >> 4;
    const int wm = (wave & 1) * 64, wn = (wave >> 1) * 64;

    __shared__ __align__(16) short As[128 * 40];
    __shared__ __align__(16) short Bs[128 * 40];

    f32x4 acc[4][4];
    #pragma unroll
    for (int i = 0; i < 4; ++i)
        #pragma unroll
        for (int j = 0; j < 4; ++j) acc[i][j] = (f32x4){0.f, 0.f, 0.f, 0.f};

    const int srow = tid >> 2;          // 0..63
    const int skq = (tid & 3) * 8;      // 0,8,16,24

    for (int k0 = 0; k0 < K; k0 += 32) {
        #pragma unroll
        for (int u = 0; u < 2; ++u) {
            int row = srow + u * 64;
            *(short8*)&As[row * 40 + skq] = *(const short8*)&A[(size_t)(bm + row) * K + k0 + skq];
            *(short8*)&Bs[row * 40 + skq] = *(const short8*)&Bt[(size_t)(bn + row) * K + k0 + skq];
        }
        __syncthreads();
        short8 af[4], bfr[4];
        #pragma unroll
        for (int i = 0; i < 4; ++i)
            af[i] = *(const short8*)&As[(wm + i * 16 + l15) * 40 + quad * 8];
        #pragma unroll
        for (int j = 0; j < 4; ++j)
            bfr[j] = *(const short8*)&Bs[(wn + j * 16 + l15) * 40 + quad * 8];
        #pragma unroll
        for (int i = 0; i < 4; ++i)
            #pragma unroll
            for (int j = 0; j < 4; ++j)
                acc[i][j] = __builtin_amdgcn_mfma_f32_16x16x32_bf16(af[i], bfr[j], acc[i][j], 0, 0, 0);
        __syncthreads();
    }

    #pragma unroll
    for (int i = 0; i < 4; ++i) {
        int row = bm + wm + i * 16 + quad * 4;
        #pragma unroll
        for (int j = 0; j < 4; ++j) {
            int col = bn + wn + j * 16 + l15;
            float bia = bias[col];
            #pragma unroll
            for (int r = 0; r < 4; ++r) {
                float v = acc[i][j][r] + bia;
                size_t idx = (size_t)(row + r) * N + col;
                if (MODE == 1) {
                    ((float*)Cv)[idx] = v + res[idx];
                } else if (MODE == 2) {
                    ((__hip_bfloat16*)Cv)[idx] = __float2bfloat16(gelu_exact(v));
                } else {
                    ((__hip_bfloat16*)Cv)[idx] = __float2bfloat16(v);
                }
            }
        }
    }
}

// ---------------- window means of q,k (bf16 in) ----------------
__global__ __launch_bounds__(512) void win_means_k(const __hip_bfloat16* __restrict__ qkv,
                                                   float* __restrict__ qkwin) {
    int w = blockIdx.x;
    int c = threadIdx.x;
    const __hip_bfloat16* base = qkv + (size_t)w * 64 * 768 + c;
    float s = 0.f;
    #pragma unroll 8
    for (int si = 0; si < 64; ++si) s += __bfloat162float(base[(size_t)si * 768]);
    qkwin[(size_t)w * 512 + c] = s * (1.f / 64.f);
}

// ---------------- routing top-k ----------------
__global__ __launch_bounds__(64) void route_k(const float* __restrict__ qkwin,
                                              int* __restrict__ ridx) {
    int w = blockIdx.x;
    int n = w / 49;
    int tid = threadIdx.x;
    __shared__ float qv[256];
    __shared__ float lg[49];
    for (int i = tid; i < 256; i += 64) qv[i] = qkwin[(size_t)w * 512 + i] * ATT_SCALE;
    __syncthreads();
    if (tid < 49) {
        const float* kp = qkwin + (size_t)(n * 49 + tid) * 512 + 256;
        float d = 0.f;
        for (int cc = 0; cc < 256; ++cc) d += qv[cc] * kp[cc];
        lg[tid] = d;
    }
    __syncthreads();
    if (tid == 0) {
        #pragma unroll
        for (int t = 0; t < 4; ++t) {
            float best = -1e30f; int bi = 0;
            for (int j = 0; j < 49; ++j)
                if (lg[j] > best) { best = lg[j]; bi = j; }
            lg[bi] = -1e30f;
            ridx[w * 4 + t] = bi;
        }
    }
}

// ---------------- MFMA attention: block = (window, head), 4 waves x 16 queries ----------------
__global__ __launch_bounds__(256) void attn_mfma_k(const short* __restrict__ qkv,
                                                   const int* __restrict__ ridx,
                                                   float* __restrict__ attn) {
    const int blk = blockIdx.x;
    const int w = blk >> 3, h = blk & 7;
    const int n = w / 49;
    const int tid = threadIdx.x;
    const int wave = tid >> 6, lane = tid & 63;
    const int l15 = lane & 15, quad = lane >> 4;

    __shared__ __align__(16) short Ks[256 * 40];       // [key][dim], pad 40
    __shared__ __align__(16) short Vt[32 * 264];       // [dim][key], pad 264
    __shared__ __align__(16) short Ps[4 * 16 * 264];   // per-wave [qrow][key], pad 264
    __shared__ int rs4[4];
    if (tid < 4) rs4[tid] = ridx[w * 4 + tid];
    __syncthreads();

    // stage K: key = 4*t chunks; per u: t=u, s=tid>>2, kq=(tid&3)*8
    {
        int s = tid >> 2, kq = (tid & 3) * 8;
        #pragma unroll
        for (int u = 0; u < 4; ++u) {
            int key = u * 64 + s;
            const short* src = qkv + ((size_t)(n * 49 + rs4[u]) * 64 + s) * 768 + 256 + h * 32 + kq;
            *(short8*)&Ks[key * 40 + kq] = *(const short8*)src;
        }
    }
    // stage V transposed: thread <-> key, 4 dim-chunks of 8
    {
        int key = tid;
        int t = key >> 6, s = key & 63;
        const short* src = qkv + ((size_t)(n * 49 + rs4[t]) * 64 + s) * 768 + 512 + h * 32;
        #pragma unroll
        for (int u = 0; u < 4; ++u) {
            short8 v = *(const short8*)(src + u * 8);
            #pragma unroll
            for (int i = 0; i < 8; ++i)
                Vt[(u * 8 + i) * 264 + key] = v[i];
        }
    }
    __syncthreads();

    // Q fragment direct from global: wave's queries = wave*16 .. +15
    const short* qp = qkv + ((size_t)w * 64 + wave * 16 + l15) * 768 + h * 32 + quad * 8;
    short8 qf = *(const short8*)qp;

    // S = Q K^T : 16 n-tiles of 16 keys
    f32x4 st[16];
    #pragma unroll
    for (int j = 0; j < 16; ++j) {
        short8 kf = *(const short8*)&Ks[(j * 16 + l15) * 40 + quad * 8];
        st[j] = __builtin_amdgcn_mfma_f32_16x16x32_bf16(qf, kf, (f32x4){0.f, 0.f, 0.f, 0.f}, 0, 0, 0);
    }

    // softmax per row (row = quad*4 + r), reduce across the 16-lane col group
    float lr[4];
    short* pw = &Ps[wave * 16 * 264];
    #pragma unroll
    for (int r = 0; r < 4; ++r) {
        float mx = -1e30f;
        #pragma unroll
        for (int j = 0; j < 16; ++j) mx = fmaxf(mx, st[j][r]);
        #pragma unroll
        for (int off = 1; off < 16; off <<= 1) mx = fmaxf(mx, __shfl_xor(mx, off));
        float sum = 0.f;
        #pragma unroll
        for (int j = 0; j < 16; ++j) {
            float p = __expf((st[j][r] - mx) * ATT_SCALE);
            sum += p;
            pw[(quad * 4 + r) * 264 + j * 16 + l15] = f2bs(p);
        }
        #pragma unroll
        for (int off = 1; off < 16; off <<= 1) sum += __shfl_xor(sum, off);
        lr[r] = sum;
    }
    __syncthreads();

    // O = P V : A-frag from Ps (m=query,k=key), B-frag from Vt (n=dim,k=key)
    f32x4 oc[2] = {(f32x4){0.f,0.f,0.f,0.f}, (f32x4){0.f,0.f,0.f,0.f}};
    #pragma unroll
    for (int kk = 0; kk < 8; ++kk) {
        short8 pf = *(const short8*)&pw[l15 * 264 + kk * 32 + quad * 8];
        #pragma unroll
        for (int jj = 0; jj < 2; ++jj) {
            short8 vf = *(const short8*)&Vt[(jj * 16 + l15) * 264 + kk * 32 + quad * 8];
            oc[jj] = __builtin_amdgcn_mfma_f32_16x16x32_bf16(pf, vf, oc[jj], 0, 0, 0);
        }
    }

    // epilogue: row = quad*4+r (query), col = jj*16+l15 (dim); divide by row sum
    float* op = attn + ((size_t)w * 64 + wave * 16) * 256 + h * 32;
    #pragma unroll
    for (int jj = 0; jj < 2; ++jj)
        #pragma unroll
        for (int r = 0; r < 4; ++r)
            op[(size_t)(quad * 4 + r) * 256 + jj * 16 + l15] = oc[jj][r] / lr[r];
}

// ---------------- LePE 5x5 depthwise conv + combine -> bf16 (image order) ----------------
__global__ __launch_bounds__(256) void lepe_k(const __hip_bfloat16* __restrict__ qkv,
                                              const float* __restrict__ attn,
                                              const float* __restrict__ lw,
                                              const float* __restrict__ lb,
                                              __hip_bfloat16* __restrict__ ywo) {
    int t = blockIdx.x;
    int c = threadIdx.x;
    int n = t / 3136, rem = t % 3136, y = rem / 56, x = rem % 56;
    float sum = lb[c];
    #pragma unroll
    for (int ky = 0; ky < 5; ++ky) {
        int yy = y + ky - 2;
        if ((unsigned)yy >= 56u) continue;
        #pragma unroll
        for (int kx = 0; kx < 5; ++kx) {
            int xx = x + kx - 2;
            if ((unsigned)xx >= 56u) continue;
            int p = (yy >> 3) * 7 + (xx >> 3);
            int si = (yy & 7) * 8 + (xx & 7);
            sum += __bfloat162float(qkv[((size_t)(n * 49 + p) * 64 + si) * 768 + 512 + c])
                 * lw[(ky * 5 + kx) * 256 + c];
        }
    }
    int p0 = (y >> 3) * 7 + (x >> 3);
    int s0 = (y & 7) * 8 + (x & 7);
    sum += attn[((size_t)(n * 49 + p0) * 64 + s0) * 256 + c];
    ywo[(size_t)t * 256 + c] = __float2bfloat16(sum);
}

extern "C" void kernel_launch(void* const* d_in, const int* in_sizes, int n_in,
                              void* d_out, int out_size, void* d_ws, size_t ws_size,
                              hipStream_t stream) {
    const float* x      = (const float*)d_in[0];
    const float* ln1_g  = (const float*)d_in[1];
    const float* ln1_b  = (const float*)d_in[2];
    const float* qkv_w  = (const float*)d_in[3];
    const float* qkv_b  = (const float*)d_in[4];
    const float* lepe_w = (const float*)d_in[5];
    const float* lepe_b = (const float*)d_in[6];
    const float* wo_w   = (const float*)d_in[7];
    const float* wo_b   = (const float*)d_in[8];
    const float* ln2_g  = (const float*)d_in[9];
    const float* ln2_b  = (const float*)d_in[10];
    const float* mlp_w1 = (const float*)d_in[11];
    const float* mlp_b1 = (const float*)d_in[12];
    const float* mlp_w2 = (const float*)d_in[13];
    const float* mlp_b2 = (const float*)d_in[14];
    float* out = (float*)d_out;

    char* ws = (char*)d_ws;
    __hip_bfloat16* wqkvT = (__hip_bfloat16*)(ws + OFF_WQKV);
    __hip_bfloat16* wwoT  = (__hip_bfloat16*)(ws + OFF_WWO);
    __hip_bfloat16* w1T   = (__hip_bfloat16*)(ws + OFF_W1);
    __hip_bfloat16* w2T   = (__hip_bfloat16*)(ws + OFF_W2);
    __hip_bfloat16* xln   = (__hip_bfloat16*)(ws + OFF_XLN);
    __hip_bfloat16* qkvb  = (__hip_bfloat16*)(ws + OFF_QKV);
    float* qkwin = (float*)(ws + OFF_QKWIN);
    int*   ridx  = (int*)(ws + OFF_RIDX);
    float* attnf = (float*)(ws + OFF_ATTN);
    __hip_bfloat16* ywo  = (__hip_bfloat16*)(ws + OFF_XLN);   // reuse
    __hip_bfloat16* h2   = (__hip_bfloat16*)(ws + OFF_ATTN);  // reuse
    __hip_bfloat16* hmid = (__hip_bfloat16*)(ws + OFF_HMID);  // reuse XLN+QKV span

    // 0. weights -> bf16 transposed (N x K)
    transpose_cast_k<<<dim3(768/32, 256/32), 256, 0, stream>>>(qkv_w, wqkvT, 256, 768);
    transpose_cast_k<<<dim3(256/32, 256/32), 256, 0, stream>>>(wo_w, wwoT, 256, 256);
    transpose_cast_k<<<dim3(1024/32, 256/32), 256, 0, stream>>>(mlp_w1, w1T, 256, 1024);
    transpose_cast_k<<<dim3(256/32, 1024/32), 256, 0, stream>>>(mlp_w2, w2T, 1024, 256);
    // 1. LN1 -> xln bf16 (window order)
    ln_bf_k<<<TOK, 256, 0, stream>>>(x, ln1_g, ln1_b, xln, 1);
    // 2. qkv GEMM -> bf16
    gemm_bf<0><<<dim3(6, 196), 256, 0, stream>>>((const short*)xln, (const short*)wqkvT,
                                                 qkv_b, nullptr, qkvb, TOK, 768, 256);
    // 3. window means
    win_means_k<<<NPW, 512, 0, stream>>>(qkvb, qkwin);
    // 4. routing
    route_k<<<NPW, 64, 0, stream>>>(qkwin, ridx);
    // 5. attention (MFMA)
    attn_mfma_k<<<NPW * 8, 256, 0, stream>>>((const short*)qkvb, ridx, attnf);
    // 6. lepe + combine -> ywo bf16 (image order)
    lepe_k<<<TOK, 256, 0, stream>>>(qkvb, attnf, lepe_w, lepe_b, ywo);
    // 7. wo GEMM + x residual -> d_out f32
    gemm_bf<1><<<dim3(2, 196), 256, 0, stream>>>((const short*)ywo, (const short*)wwoT,
                                                 wo_b, x, out, TOK, 256, 256);
    // 8. LN2 -> h2 bf16
    ln_bf_k<<<TOK, 256, 0, stream>>>(out, ln2_g, ln2_b, h2, 0);
    // 9. MLP1 GEMM + gelu -> hmid bf16
    gemm_bf<2><<<dim3(8, 196), 256, 0, stream>>>((const short*)h2, (const short*)w1T,
                                                 mlp_b1, nullptr, hmid, TOK, 1024, 256);
    // 10. MLP2 GEMM + bias + residual -> d_out f32
    gemm_bf<1><<<dim3(2, 196), 256, 0, stream>>>((const short*)hmid, (const short*)w2T,
                                                 mlp_b2, out, out, TOK, 256, 1024);
}

// Round 3
// 350.209 us; speedup vs baseline: 3.9128x; 1.2467x over previous
//
#include <hip/hip_runtime.h>
#include <hip/hip_bf16.h>

#define NIMG 8
#define HW 56
#define CDIM 256
#define TOK (NIMG*HW*HW)        // 25088
#define NWIN 49
#define NPW (NIMG*NWIN)         // 392
#define ATT_SCALE 0.0625f       // 256^-0.5

typedef __attribute__((ext_vector_type(8))) short short8;
typedef __attribute__((ext_vector_type(4))) short short4v;
typedef __attribute__((ext_vector_type(4))) float f32x4;

// ---- workspace layout (bytes, 16B aligned) ----
static const size_t OFF_WQKV  = 0;           // 768x256 bf16
static const size_t OFF_WWO   = 393216;      // 256x256 bf16
static const size_t OFF_W1    = 524288;      // 1024x256 bf16
static const size_t OFF_W2    = 1048576;     // 256x1024 bf16
static const size_t OFF_XLN   = 1572864;     // 25088x256 bf16 (reused: ywo_bf; with QKV as hmid)
static const size_t OFF_QKV   = 14417920;    // 25088x768 bf16
static const size_t OFF_QKWIN = 52953088;    // 392x512 f32
static const size_t OFF_RIDX  = 53755904;    // 392x4 int
static const size_t OFF_ATTN  = 53762176;    // 25088x256 bf16 (reused: h2_bf)
static const size_t OFF_HMID  = OFF_XLN;     // 25088x1024 bf16 spans XLN+QKV regions

__device__ __forceinline__ float gelu_exact(float v) {
    return 0.5f * v * (1.f + erff(v * 0.70710678118654752f));
}
__device__ __forceinline__ short f2bs(float x) {
    __hip_bfloat16 h = __float2bfloat16(x);
    return *(short*)&h;
}
__device__ __forceinline__ float bs2f(short s) {
    return __uint_as_float(((unsigned)(unsigned short)s) << 16);
}

// ---------------- weight transpose + cast: src K x N f32 -> dst N x K bf16 ----------------
__global__ __launch_bounds__(256) void transpose_cast_k(const float* __restrict__ src,
                                                        __hip_bfloat16* __restrict__ dst,
                                                        int K, int N) {
    __shared__ float t[32][33];
    int n0 = blockIdx.x * 32, k0 = blockIdx.y * 32;
    int tx = threadIdx.x & 31, ty = threadIdx.x >> 5;   // 32 x 8
    #pragma unroll
    for (int i = 0; i < 32; i += 8)
        t[ty + i][tx] = src[(size_t)(k0 + ty + i) * N + n0 + tx];
    __syncthreads();
    #pragma unroll
    for (int i = 0; i < 32; i += 8)
        dst[(size_t)(n0 + ty + i) * K + k0 + tx] = __float2bfloat16(t[tx][ty + i]);
}

// ---------------- LayerNorm: wave per token, lane = 4 channels ----------------
__global__ __launch_bounds__(256) void ln_bf_k(const float* __restrict__ in,
                                               const float* __restrict__ g,
                                               const float* __restrict__ b,
                                               short* __restrict__ out, int remap) {
    int t = blockIdx.x * 4 + (threadIdx.x >> 6);
    int lane = threadIdx.x & 63;
    float4 v = *(const float4*)(in + (size_t)t * 256 + lane * 4);
    float s = v.x + v.y + v.z + v.w;
    float s2 = v.x * v.x + v.y * v.y + v.z * v.z + v.w * v.w;
    #pragma unroll
    for (int o = 32; o > 0; o >>= 1) {
        s  += __shfl_xor(s, o);
        s2 += __shfl_xor(s2, o);
    }
    float mu = s * (1.f / 256.f);
    float rstd = rsqrtf(s2 * (1.f / 256.f) - mu * mu + 1e-6f);
    float4 gv = *(const float4*)(g + lane * 4);
    float4 bv = *(const float4*)(b + lane * 4);
    short4v o;
    o[0] = f2bs((v.x - mu) * rstd * gv.x + bv.x);
    o[1] = f2bs((v.y - mu) * rstd * gv.y + bv.y);
    o[2] = f2bs((v.z - mu) * rstd * gv.z + bv.z);
    o[3] = f2bs((v.w - mu) * rstd * gv.w + bv.w);
    size_t tb;
    if (remap) {
        int n = t / 3136, rem = t % 3136, y = rem / 56, x = rem % 56;
        int p = (y >> 3) * 7 + (x >> 3);
        int si = (y & 7) * 8 + (x & 7);
        tb = (size_t)(n * 49 + p) * 64 + si;
    } else {
        tb = (size_t)t;
    }
    *(short4v*)(out + tb * 256 + lane * 4) = o;
}

// ---------------- bf16 MFMA GEMM: C[M,N] = A[M,K] @ Bt[N,K]^T ----------------
// MODE 0: bf16 out, +bias. MODE 1: f32 out, +bias+res. MODE 2: bf16 out, gelu(+bias).
template<int MODE>
__global__ __launch_bounds__(256) void gemm_bf(const short* __restrict__ A,
                                               const short* __restrict__ Bt,
                                               const float* __restrict__ bias,
                                               const float* __restrict__ res, void* Cv,
                                               int M, int N, int K) {
    const int bn = blockIdx.x * 128;
    const int bm = blockIdx.y * 128;
    const int tid = threadIdx.x;
    const int wave = tid >> 6, lane = tid & 63;
    const int l15 = lane & 15, quad = lane >> 4;
    const int wm = (wave & 1) * 64, wn = (wave >> 1) * 64;

    __shared__ __align__(16) short As[128 * 40];
    __shared__ __align__(16) short Bs[128 * 40];

    f32x4 acc[4][4];
    #pragma unroll
    for (int i = 0; i < 4; ++i)
        #pragma unroll
        for (int j = 0; j < 4; ++j) acc[i][j] = (f32x4){0.f, 0.f, 0.f, 0.f};

    const int srow = tid >> 2;          // 0..63
    const int skq = (tid & 3) * 8;      // 0,8,16,24

    for (int k0 = 0; k0 < K; k0 += 32) {
        #pragma unroll
        for (int u = 0; u < 2; ++u) {
            int row = srow + u * 64;
            *(short8*)&As[row * 40 + skq] = *(const short8*)&A[(size_t)(bm + row) * K + k0 + skq];
            *(short8*)&Bs[row * 40 + skq] = *(const short8*)&Bt[(size_t)(bn + row) * K + k0 + skq];
        }
        __syncthreads();
        short8 af[4], bfr[4];
        #pragma unroll
        for (int i = 0; i < 4; ++i)
            af[i] = *(const short8*)&As[(wm + i * 16 + l15) * 40 + quad * 8];
        #pragma unroll
        for (int j = 0; j < 4; ++j)
            bfr[j] = *(const short8*)&Bs[(wn + j * 16 + l15) * 40 + quad * 8];
        #pragma unroll
        for (int i = 0; i < 4; ++i)
            #pragma unroll
            for (int j = 0; j < 4; ++j)
                acc[i][j] = __builtin_amdgcn_mfma_f32_16x16x32_bf16(af[i], bfr[j], acc[i][j], 0, 0, 0);
        __syncthreads();
    }

    #pragma unroll
    for (int i = 0; i < 4; ++i) {
        int row = bm + wm + i * 16 + quad * 4;
        #pragma unroll
        for (int j = 0; j < 4; ++j) {
            int col = bn + wn + j * 16 + l15;
            float bia = bias[col];
            #pragma unroll
            for (int r = 0; r < 4; ++r) {
                float v = acc[i][j][r] + bia;
                size_t idx = (size_t)(row + r) * N + col;
                if (MODE == 1) {
                    ((float*)Cv)[idx] = v + res[idx];
                } else if (MODE == 2) {
                    ((__hip_bfloat16*)Cv)[idx] = __float2bfloat16(gelu_exact(v));
                } else {
                    ((__hip_bfloat16*)Cv)[idx] = __float2bfloat16(v);
                }
            }
        }
    }
}

// ---------------- window means of q,k: block per window, short8 loads ----------------
__global__ __launch_bounds__(256) void win_means_k(const short* __restrict__ qkv,
                                                   float* __restrict__ qkwin) {
    int w = blockIdx.x;
    int cg = (threadIdx.x & 63) * 8;    // channel offset 0..504
    int sp = threadIdx.x >> 6;          // 0..3
    float s[8] = {0.f, 0.f, 0.f, 0.f, 0.f, 0.f, 0.f, 0.f};
    const short* base = qkv + (size_t)w * 64 * 768 + cg;
    for (int si = sp; si < 64; si += 4) {
        short8 v = *(const short8*)(base + (size_t)si * 768);
        #pragma unroll
        for (int i = 0; i < 8; ++i) s[i] += bs2f(v[i]);
    }
    __shared__ float red[4][512];
    #pragma unroll
    for (int i = 0; i < 8; ++i) red[sp][cg + i] = s[i];
    __syncthreads();
    for (int c = threadIdx.x; c < 512; c += 256) {
        float t = red[0][c] + red[1][c] + red[2][c] + red[3][c];
        qkwin[(size_t)w * 512 + c] = t * (1.f / 64.f);
    }
}

// ---------------- routing top-k ----------------
__global__ __launch_bounds__(64) void route_k(const float* __restrict__ qkwin,
                                              int* __restrict__ ridx) {
    int w = blockIdx.x;
    int n = w / 49;
    int tid = threadIdx.x;
    __shared__ float qv[256];
    __shared__ float lg[49];
    for (int i = tid; i < 256; i += 64) qv[i] = qkwin[(size_t)w * 512 + i] * ATT_SCALE;
    __syncthreads();
    if (tid < 49) {
        const float* kp = qkwin + (size_t)(n * 49 + tid) * 512 + 256;
        float d = 0.f;
        for (int cc = 0; cc < 256; ++cc) d += qv[cc] * kp[cc];
        lg[tid] = d;
    }
    __syncthreads();
    if (tid == 0) {
        #pragma unroll
        for (int t = 0; t < 4; ++t) {
            float best = -1e30f; int bi = 0;
            for (int j = 0; j < 49; ++j)
                if (lg[j] > best) { best = lg[j]; bi = j; }
            lg[bi] = -1e30f;
            ridx[w * 4 + t] = bi;
        }
    }
}

// ---------------- MFMA attention: block = (window, head), 4 waves x 16 queries ----------------
__global__ __launch_bounds__(256) void attn_mfma_k(const short* __restrict__ qkv,
                                                   const int* __restrict__ ridx,
                                                   short* __restrict__ attn) {
    const int blk = blockIdx.x;
    const int w = blk >> 3, h = blk & 7;
    const int n = w / 49;
    const int tid = threadIdx.x;
    const int wave = tid >> 6, lane = tid & 63;
    const int l15 = lane & 15, quad = lane >> 4;

    __shared__ __align__(16) short Ks[256 * 40];       // [key][dim], pad 40
    __shared__ __align__(16) short Vt[32 * 264];       // [dim][key], pad 264
    __shared__ __align__(16) short Ps[4 * 16 * 264];   // per-wave [qrow][key], pad 264
    __shared__ int rs4[4];
    if (tid < 4) rs4[tid] = ridx[w * 4 + tid];
    __syncthreads();

    // stage K
    {
        int s = tid >> 2, kq = (tid & 3) * 8;
        #pragma unroll
        for (int u = 0; u < 4; ++u) {
            int key = u * 64 + s;
            const short* src = qkv + ((size_t)(n * 49 + rs4[u]) * 64 + s) * 768 + 256 + h * 32 + kq;
            *(short8*)&Ks[key * 40 + kq] = *(const short8*)src;
        }
    }
    // stage V transposed
    {
        int key = tid;
        int t = key >> 6, s = key & 63;
        const short* src = qkv + ((size_t)(n * 49 + rs4[t]) * 64 + s) * 768 + 512 + h * 32;
        #pragma unroll
        for (int u = 0; u < 4; ++u) {
            short8 v = *(const short8*)(src + u * 8);
            #pragma unroll
            for (int i = 0; i < 8; ++i)
                Vt[(u * 8 + i) * 264 + key] = v[i];
        }
    }
    __syncthreads();

    // Q fragment direct from global
    const short* qp = qkv + ((size_t)w * 64 + wave * 16 + l15) * 768 + h * 32 + quad * 8;
    short8 qf = *(const short8*)qp;

    // S = Q K^T
    f32x4 st[16];
    #pragma unroll
    for (int j = 0; j < 16; ++j) {
        short8 kf = *(const short8*)&Ks[(j * 16 + l15) * 40 + quad * 8];
        st[j] = __builtin_amdgcn_mfma_f32_16x16x32_bf16(qf, kf, (f32x4){0.f, 0.f, 0.f, 0.f}, 0, 0, 0);
    }

    // softmax per row
    float lr[4];
    short* pw = &Ps[wave * 16 * 264];
    #pragma unroll
    for (int r = 0; r < 4; ++r) {
        float mx = -1e30f;
        #pragma unroll
        for (int j = 0; j < 16; ++j) mx = fmaxf(mx, st[j][r]);
        #pragma unroll
        for (int off = 1; off < 16; off <<= 1) mx = fmaxf(mx, __shfl_xor(mx, off));
        float sum = 0.f;
        #pragma unroll
        for (int j = 0; j < 16; ++j) {
            float p = __expf((st[j][r] - mx) * ATT_SCALE);
            sum += p;
            pw[(quad * 4 + r) * 264 + j * 16 + l15] = f2bs(p);
        }
        #pragma unroll
        for (int off = 1; off < 16; off <<= 1) sum += __shfl_xor(sum, off);
        lr[r] = sum;
    }
    __syncthreads();

    // O = P V
    f32x4 oc[2] = {(f32x4){0.f,0.f,0.f,0.f}, (f32x4){0.f,0.f,0.f,0.f}};
    #pragma unroll
    for (int kk = 0; kk < 8; ++kk) {
        short8 pf = *(const short8*)&pw[l15 * 264 + kk * 32 + quad * 8];
        #pragma unroll
        for (int jj = 0; jj < 2; ++jj) {
            short8 vf = *(const short8*)&Vt[(jj * 16 + l15) * 264 + kk * 32 + quad * 8];
            oc[jj] = __builtin_amdgcn_mfma_f32_16x16x32_bf16(pf, vf, oc[jj], 0, 0, 0);
        }
    }

    // epilogue -> bf16
    short* op = attn + ((size_t)w * 64 + wave * 16) * 256 + h * 32;
    #pragma unroll
    for (int jj = 0; jj < 2; ++jj)
        #pragma unroll
        for (int r = 0; r < 4; ++r)
            op[(size_t)(quad * 4 + r) * 256 + jj * 16 + l15] = f2bs(oc[jj][r] / lr[r]);
}

// ---------------- LePE 5x5 dwconv + combine (vectorized 8-ch per thread) ----------------
__global__ __launch_bounds__(256) void lepe_k(const short* __restrict__ qkv,
                                              const short* __restrict__ attn,
                                              const float* __restrict__ lw,
                                              const float* __restrict__ lb,
                                              short* __restrict__ ywo) {
    int t = blockIdx.x * 8 + (threadIdx.x >> 5);
    int c0 = (threadIdx.x & 31) * 8;
    int n = t / 3136, rem = t % 3136, y = rem / 56, x = rem % 56;
    float sum[8];
    {
        float4 b0 = *(const float4*)(lb + c0), b1 = *(const float4*)(lb + c0 + 4);
        sum[0] = b0.x; sum[1] = b0.y; sum[2] = b0.z; sum[3] = b0.w;
        sum[4] = b1.x; sum[5] = b1.y; sum[6] = b1.z; sum[7] = b1.w;
    }
    #pragma unroll
    for (int ky = 0; ky < 5; ++ky) {
        int yy = y + ky - 2;
        if ((unsigned)yy >= 56u) continue;
        #pragma unroll
        for (int kx = 0; kx < 5; ++kx) {
            int xx = x + kx - 2;
            if ((unsigned)xx >= 56u) continue;
            int p = (yy >> 3) * 7 + (xx >> 3);
            int si = (yy & 7) * 8 + (xx & 7);
            short8 v = *(const short8*)(qkv + ((size_t)(n * 49 + p) * 64 + si) * 768 + 512 + c0);
            const float* wp = lw + (ky * 5 + kx) * 256 + c0;
            float4 w0 = *(const float4*)wp, w1 = *(const float4*)(wp + 4);
            sum[0] += bs2f(v[0]) * w0.x; sum[1] += bs2f(v[1]) * w0.y;
            sum[2] += bs2f(v[2]) * w0.z; sum[3] += bs2f(v[3]) * w0.w;
            sum[4] += bs2f(v[4]) * w1.x; sum[5] += bs2f(v[5]) * w1.y;
            sum[6] += bs2f(v[6]) * w1.z; sum[7] += bs2f(v[7]) * w1.w;
        }
    }
    int p0 = (y >> 3) * 7 + (x >> 3);
    int s0 = (y & 7) * 8 + (x & 7);
    short8 a = *(const short8*)(attn + ((size_t)(n * 49 + p0) * 64 + s0) * 256 + c0);
    short8 o;
    #pragma unroll
    for (int i = 0; i < 8; ++i) o[i] = f2bs(sum[i] + bs2f(a[i]));
    *(short8*)(ywo + (size_t)t * 256 + c0) = o;
}

extern "C" void kernel_launch(void* const* d_in, const int* in_sizes, int n_in,
                              void* d_out, int out_size, void* d_ws, size_t ws_size,
                              hipStream_t stream) {
    const float* x      = (const float*)d_in[0];
    const float* ln1_g  = (const float*)d_in[1];
    const float* ln1_b  = (const float*)d_in[2];
    const float* qkv_w  = (const float*)d_in[3];
    const float* qkv_b  = (const float*)d_in[4];
    const float* lepe_w = (const float*)d_in[5];
    const float* lepe_b = (const float*)d_in[6];
    const float* wo_w   = (const float*)d_in[7];
    const float* wo_b   = (const float*)d_in[8];
    const float* ln2_g  = (const float*)d_in[9];
    const float* ln2_b  = (const float*)d_in[10];
    const float* mlp_w1 = (const float*)d_in[11];
    const float* mlp_b1 = (const float*)d_in[12];
    const float* mlp_w2 = (const float*)d_in[13];
    const float* mlp_b2 = (const float*)d_in[14];
    float* out = (float*)d_out;

    char* ws = (char*)d_ws;
    __hip_bfloat16* wqkvT = (__hip_bfloat16*)(ws + OFF_WQKV);
    __hip_bfloat16* wwoT  = (__hip_bfloat16*)(ws + OFF_WWO);
    __hip_bfloat16* w1T   = (__hip_bfloat16*)(ws + OFF_W1);
    __hip_bfloat16* w2T   = (__hip_bfloat16*)(ws + OFF_W2);
    short* xln   = (short*)(ws + OFF_XLN);
    short* qkvb  = (short*)(ws + OFF_QKV);
    float* qkwin = (float*)(ws + OFF_QKWIN);
    int*   ridx  = (int*)(ws + OFF_RIDX);
    short* attnb = (short*)(ws + OFF_ATTN);
    short* ywo   = (short*)(ws + OFF_XLN);    // reuse
    short* h2    = (short*)(ws + OFF_ATTN);   // reuse
    short* hmid  = (short*)(ws + OFF_HMID);   // reuse XLN+QKV span

    // 0. weights -> bf16 transposed (N x K)
    transpose_cast_k<<<dim3(768/32, 256/32), 256, 0, stream>>>(qkv_w, wqkvT, 256, 768);
    transpose_cast_k<<<dim3(256/32, 256/32), 256, 0, stream>>>(wo_w, wwoT, 256, 256);
    transpose_cast_k<<<dim3(1024/32, 256/32), 256, 0, stream>>>(mlp_w1, w1T, 256, 1024);
    transpose_cast_k<<<dim3(256/32, 1024/32), 256, 0, stream>>>(mlp_w2, w2T, 1024, 256);
    // 1. LN1 -> xln bf16 (window order)
    ln_bf_k<<<TOK/4, 256, 0, stream>>>(x, ln1_g, ln1_b, xln, 1);
    // 2. qkv GEMM -> bf16
    gemm_bf<0><<<dim3(6, 196), 256, 0, stream>>>(xln, (const short*)wqkvT,
                                                 qkv_b, nullptr, qkvb, TOK, 768, 256);
    // 3. window means
    win_means_k<<<NPW, 256, 0, stream>>>(qkvb, qkwin);
    // 4. routing
    route_k<<<NPW, 64, 0, stream>>>(qkwin, ridx);
    // 5. attention (MFMA) -> bf16
    attn_mfma_k<<<NPW * 8, 256, 0, stream>>>(qkvb, ridx, attnb);
    // 6. lepe + combine -> ywo bf16 (image order)
    lepe_k<<<TOK/8, 256, 0, stream>>>(qkvb, attnb, lepe_w, lepe_b, ywo);
    // 7. wo GEMM + x residual -> d_out f32
    gemm_bf<1><<<dim3(2, 196), 256, 0, stream>>>(ywo, (const short*)wwoT,
                                                 wo_b, x, out, TOK, 256, 256);
    // 8. LN2 -> h2 bf16
    ln_bf_k<<<TOK/4, 256, 0, stream>>>(out, ln2_g, ln2_b, h2, 0);
    // 9. MLP1 GEMM + gelu -> hmid bf16
    gemm_bf<2><<<dim3(8, 196), 256, 0, stream>>>(h2, (const short*)w1T,
                                                 mlp_b1, nullptr, hmid, TOK, 1024, 256);
    // 10. MLP2 GEMM + bias + residual -> d_out f32
    gemm_bf<1><<<dim3(2, 196), 256, 0, stream>>>(hmid, (const short*)w2T,
                                                 mlp_b2, out, out, TOK, 256, 1024);
}